// Round 13
// baseline (552.372 us; speedup 1.0000x reference)
//
#include <hip/hip_runtime.h>

#define B_ 8
#define S_ 4096
#define T_ 2048
#define C_ 256
#define Q_ 256
#define NROW (T_ * B_)

typedef _Float16 f16;
typedef _Float16 f16x8 __attribute__((ext_vector_type(8)));
typedef _Float16 f16x4 __attribute__((ext_vector_type(4)));
typedef _Float16 f16x2 __attribute__((ext_vector_type(2)));
typedef float f32x4 __attribute__((ext_vector_type(4)));

#define MFMA(a, b, c) __builtin_amdgcn_mfma_f32_16x16x32_f16((a), (b), (c), 0, 0, 0)

// ---------------- mask dtype sniff (device-side, deterministic) ----------------
// mode: 0 = int32, 1 = bytes (bool/uint8), 2 = float32, 3 = all-zero (no mask)
__global__ void k_mask_mode(const unsigned char* __restrict__ mb, int* __restrict__ mode,
                            int* __restrict__ allm) {
  __shared__ int s0_, s123_;
  if (threadIdx.x == 0) { s0_ = 0; s123_ = 0; }
  __syncthreads();
  int a0 = 0, a123 = 0;
  int base = threadIdx.x * 128;
  for (int i = 0; i < 128; ++i) {
    int idx = base + i;
    int v = mb[idx];
    if (idx & 3) a123 |= v; else a0 |= v;
  }
  if (a0) atomicOr(&s0_, 1);
  if (a123) atomicOr(&s123_, 1);
  __syncthreads();
  if (threadIdx.x == 0) {
    int m;
    if (s123_ == 0 && s0_ == 0) m = 3;
    else if (s123_ == 0) m = 0;
    else if (s0_ == 0) m = 2;
    else m = 1;
    *mode = m;
  }
  if (threadIdx.x < B_) allm[threadIdx.x] = 1;
}

__global__ void k_expand_mask(const void* __restrict__ mp, const int* __restrict__ mode,
                              float* __restrict__ maskf, int* __restrict__ allm) {
  int i = blockIdx.x * 256 + threadIdx.x;  // B_*S_ total
  int md = *mode;
  int m;
  if (md == 0)      m = ((const int*)mp)[i] != 0;
  else if (md == 1) m = ((const unsigned char*)mp)[i] != 0;
  else if (md == 2) m = ((const float*)mp)[i] != 0.0f;
  else              m = 0;
  maskf[i] = m ? 1.0f : 0.0f;
  if (!m) atomicAnd(&allm[i / S_], 0);
}

// ---------------- conversions ----------------
__global__ void k_conv_w(const float* __restrict__ W, f16* __restrict__ WT) {
  int i = blockIdx.x * 256 + threadIdx.x;  // C_*Q_
  int c = i >> 8, q = i & 255;
  WT[q * C_ + c] = (f16)W[i];
}

__global__ void k_conv_q(const float* __restrict__ q, f16* __restrict__ qT) {
  int i = blockIdx.x * 256 + threadIdx.x;  // T_*B_*Q_/4 threads
  int e = i * 4;
  int t = e / (B_ * Q_);
  int rb = e - t * (B_ * Q_);
  int b = rb >> 8;
  int qq = rb & 255;
  f32x4 v = *(const f32x4*)(q + e);
  f16x4 h; h[0] = (f16)v[0]; h[1] = (f16)v[1]; h[2] = (f16)v[2]; h[3] = (f16)v[3];
  *(f16x4*)(qT + ((size_t)(b * T_ + t)) * Q_ + qq) = h;
}

// ctx [b][s][c] f32 -> ctxT [b][c][s] f16, 64x64 tiles via LDS
__global__ void k_transpose_ctx(const float* __restrict__ ctx, f16* __restrict__ ctxT) {
  __shared__ f16 tile[64][65];
  int s0 = blockIdx.x * 64, c0 = blockIdx.y * 64, b = blockIdx.z;
  int r = threadIdx.x >> 2;
  int cs = (threadIdx.x & 3) * 16;
  const float* src = ctx + ((size_t)(b * S_ + s0 + r)) * C_ + c0 + cs;
  f32x4 v0 = ((const f32x4*)src)[0];
  f32x4 v1 = ((const f32x4*)src)[1];
  f32x4 v2 = ((const f32x4*)src)[2];
  f32x4 v3 = ((const f32x4*)src)[3];
#pragma unroll
  for (int j = 0; j < 4; ++j) {
    tile[r][cs + j] = (f16)v0[j];
    tile[r][cs + 4 + j] = (f16)v1[j];
    tile[r][cs + 8 + j] = (f16)v2[j];
    tile[r][cs + 12 + j] = (f16)v3[j];
  }
  __syncthreads();
  int c = threadIdx.x >> 2;
  int ss = (threadIdx.x & 3) * 16;
  f16x8 o0, o1;
#pragma unroll
  for (int j = 0; j < 8; ++j) { o0[j] = tile[ss + j][c]; o1[j] = tile[ss + 8 + j][c]; }
  f16* dst = ctxT + ((size_t)(b * C_ + c0 + c)) * S_ + s0 + ss;
  *(f16x8*)dst = o0;
  *(f16x8*)(dst + 8) = o1;
}

// ---------------- GEMM 1: CW[m=(b,s)][q] = ctx @ W^T, scaled 1/16, f16 out ----------------
__launch_bounds__(256, 2)
__global__ void k_gemm_cw(const float* __restrict__ ctx, const f16* __restrict__ WT,
                          f16* __restrict__ CW) {
  __shared__ alignas(16) f16 As[128 * 32];
  __shared__ alignas(16) f16 Bs[128 * 32];
  int n0 = blockIdx.x * 128;  // q
  int m0 = blockIdx.y * 128;  // flat (b,s)
  int tid = threadIdx.x;
  int w = tid >> 6, l = tid & 63;
  int wm = (w >> 1) * 64, wn = (w & 1) * 64;
  int lr = l & 15, lk = (l >> 4) * 8;
  f32x4 acc[4][4] = {};
  for (int k0 = 0; k0 < C_; k0 += 32) {
    __syncthreads();
#pragma unroll
    for (int it = 0; it < 2; ++it) {
      int h = (it * 256 + tid) * 8;
      int row = h >> 5, kk = h & 31;
      const float* ap = ctx + (size_t)(m0 + row) * C_ + k0 + kk;
      f32x4 x0 = ((const f32x4*)ap)[0];
      f32x4 x1 = ((const f32x4*)ap)[1];
      f16x8 hv;
#pragma unroll
      for (int j = 0; j < 4; ++j) { hv[j] = (f16)x0[j]; hv[4 + j] = (f16)x1[j]; }
      *(f16x8*)&As[row * 32 + kk] = hv;
    }
#pragma unroll
    for (int it = 0; it < 2; ++it) {
      int h = (it * 256 + tid) * 8;
      int row = h >> 5, kk = h & 31;
      *(f16x8*)&Bs[row * 32 + kk] = *(const f16x8*)&WT[(size_t)(n0 + row) * C_ + k0 + kk];
    }
    __syncthreads();
    f16x8 af[4], bf[4];
#pragma unroll
    for (int m = 0; m < 4; ++m) af[m] = *(const f16x8*)&As[(wm + m * 16 + lr) * 32 + lk];
#pragma unroll
    for (int n = 0; n < 4; ++n) bf[n] = *(const f16x8*)&Bs[(wn + n * 16 + lr) * 32 + lk];
#pragma unroll
    for (int m = 0; m < 4; ++m)
#pragma unroll
      for (int n = 0; n < 4; ++n) acc[m][n] = MFMA(af[m], bf[n], acc[m][n]);
  }
#pragma unroll
  for (int m = 0; m < 4; ++m)
#pragma unroll
    for (int n = 0; n < 4; ++n)
#pragma unroll
      for (int i = 0; i < 4; ++i) {
        int gm = m0 + wm + m * 16 + (l >> 4) * 4 + i;
        int gn = n0 + wn + n * 16 + lr;
        CW[(size_t)gm * Q_ + gn] = (f16)(acc[m][n][i] * 0.0625f);
      }
}

// ---------------- OLD GEMM 2 (fallback path): scores + raw attn store + stats ----------------
__launch_bounds__(256, 2)
__global__ void k_gemm_scores(const f16* __restrict__ qT, const f16* __restrict__ CW,
                              const float* __restrict__ maskf, float* __restrict__ attn,
                              float* __restrict__ pmax, float* __restrict__ psum) {
  __shared__ alignas(16) f16 As[128 * 32];
  __shared__ alignas(16) f16 Bs[128 * 32];
  int n0 = blockIdx.x * 128;  // s
  int m0 = blockIdx.y * 128;  // t
  int b = blockIdx.z;
  const f16* A = qT + (size_t)b * T_ * Q_;
  const f16* Bm = CW + (size_t)b * S_ * Q_;
  int tid = threadIdx.x;
  int w = tid >> 6, l = tid & 63;
  int wm = (w >> 1) * 64, wn = (w & 1) * 64;
  int lr = l & 15, lk = (l >> 4) * 8;
  f32x4 acc[4][4] = {};
  for (int k0 = 0; k0 < Q_; k0 += 32) {
    __syncthreads();
#pragma unroll
    for (int it = 0; it < 2; ++it) {
      int h = (it * 256 + tid) * 8;
      int row = h >> 5, kk = h & 31;
      *(f16x8*)&As[row * 32 + kk] = *(const f16x8*)&A[(size_t)(m0 + row) * Q_ + k0 + kk];
    }
#pragma unroll
    for (int it = 0; it < 2; ++it) {
      int h = (it * 256 + tid) * 8;
      int row = h >> 5, kk = h & 31;
      *(f16x8*)&Bs[row * 32 + kk] = *(const f16x8*)&Bm[(size_t)(n0 + row) * Q_ + k0 + kk];
    }
    __syncthreads();
    f16x8 af[4], bf[4];
#pragma unroll
    for (int m = 0; m < 4; ++m) af[m] = *(const f16x8*)&As[(wm + m * 16 + lr) * 32 + lk];
#pragma unroll
    for (int n = 0; n < 4; ++n) bf[n] = *(const f16x8*)&Bs[(wn + n * 16 + lr) * 32 + lk];
#pragma unroll
    for (int m = 0; m < 4; ++m)
#pragma unroll
      for (int n = 0; n < 4; ++n) acc[m][n] = MFMA(af[m], bf[n], acc[m][n]);
  }
  float msk[4];
#pragma unroll
  for (int n = 0; n < 4; ++n) msk[n] = maskf[b * S_ + n0 + wn + n * 16 + lr];
#pragma unroll
  for (int m = 0; m < 4; ++m)
#pragma unroll
    for (int n = 0; n < 4; ++n) {
      int gn = n0 + wn + n * 16 + lr;
#pragma unroll
      for (int i = 0; i < 4; ++i) {
        int gt = m0 + wm + m * 16 + (l >> 4) * 4 + i;
        float v = acc[m][n][i];
        if (msk[n] != 0.0f) v = -3.4e38f;
        acc[m][n][i] = v;
        attn[((size_t)gt * B_ + b) * S_ + gn] = v;
      }
    }
  int g = l >> 4;
  int ch = blockIdx.x * 2 + (w & 1);
#pragma unroll
  for (int m = 0; m < 4; ++m)
#pragma unroll
    for (int i = 0; i < 4; ++i) {
      float mx = fmaxf(fmaxf(acc[m][0][i], acc[m][1][i]), fmaxf(acc[m][2][i], acc[m][3][i]));
      mx = fmaxf(mx, __shfl_xor(mx, 1));
      mx = fmaxf(mx, __shfl_xor(mx, 2));
      mx = fmaxf(mx, __shfl_xor(mx, 4));
      mx = fmaxf(mx, __shfl_xor(mx, 8));
      float sm = 0.0f;
#pragma unroll
      for (int n = 0; n < 4; ++n) sm += __expf(acc[m][n][i] - mx);
      sm += __shfl_xor(sm, 1);
      sm += __shfl_xor(sm, 2);
      sm += __shfl_xor(sm, 4);
      sm += __shfl_xor(sm, 8);
      if (lr == 0) {
        int gt = m0 + wm + m * 16 + g * 4 + i;
        int r = gt * B_ + b;
        pmax[ch * NROW + r] = mx;
        psum[ch * NROW + r] = sm;
      }
    }
}

// ---------------- pass A v6: stats = fused4's scores phase, stripped ----------------
// R12 insight: four stats stagings all ~200us, but fused4 does scores+comp+stores in
// 206us. So stats6 IS fused4's scores structure: Qs LDS-resident (identical staging),
// CW streamed from L2 in 256-s slabs, ZERO barriers in the loop (Qs read-only, no Ps).
// Wave mapping = original stats' 64x64 (wave holds 64 s-cols -> 64-chunk reduce stays
// wave-local; shuffle-reduce code identical to the proven original). Per-element
// kq-ascending MFMA chain -> scores/stats bitwise identical to fused4.
// Grid 16 t-blocks x 4 s-quarters x B = 512 blocks, 512 thr, LDS 64KB.
__launch_bounds__(512, 2)
__global__ void k_stats6(const f16* __restrict__ qT, const f16* __restrict__ CW,
                         const float* __restrict__ maskf,
                         float* __restrict__ pmax, float* __restrict__ psum) {
  __shared__ alignas(16) f16 Qs[128 * 256];  // 64 KB, 512B rows, XOR-swizzled
  const int bid = blockIdx.x;
  const int b = bid & 7;                     // XCD pin
  const int u = bid >> 3;                    // 0..63
  const int t0 = (u & 15) * 128;
  const int sp = u >> 4;                     // 0..3
  const int sbase = sp * (S_ / 4);           // 1024
  const int tid = threadIdx.x;               // 0..511
  const int w = tid >> 6, l = tid & 63;
  const int lr = l & 15, hi = l >> 4;
  const int wm = (w & 1) * 64;               // t-row base within 128-tile (half)
  const int cbase = (w >> 1) * 64;           // s-col base within 256-slab (chunk)
  // ---- stage Qs (identical to fused4) ----
  {
    const int qr = tid & 127;
    const int cb0 = (tid >> 7) * 128;
    const char* src = (const char*)(qT + ((size_t)(b * T_ + t0 + qr)) * Q_) + cb0;
#pragma unroll
    for (int j = 0; j < 8; ++j) {
      f16x8 v = *(const f16x8*)(src + j * 16);
      *(f16x8*)((char*)Qs + qr * 512 + ((cb0 + j * 16) ^ ((qr & 7) << 4))) = v;
    }
  }
  const f16* cwB = CW + (size_t)b * S_ * Q_;
  __syncthreads();
  for (int is = 0; is < 4; ++is) {  // 4 slabs of 256 s per block
    const int s00 = sbase + is * 256;
    f32x4 acc[4][4] = {};
#pragma unroll
    for (int kq = 0; kq < 8; ++kq) {
      f16x8 bf[4];
#pragma unroll
      for (int n = 0; n < 4; ++n)
        bf[n] = *(const f16x8*)(cwB + (size_t)(s00 + cbase + n * 16 + lr) * Q_ +
                                kq * 32 + hi * 8);
#pragma unroll
      for (int m = 0; m < 4; ++m) {
        f16x8 af = *(const f16x8*)((char*)Qs + (wm + m * 16 + lr) * 512 +
                                   ((kq * 64 + hi * 16) ^ ((lr & 7) << 4)));
#pragma unroll
        for (int n = 0; n < 4; ++n) acc[m][n] = MFMA(af, bf[n], acc[m][n]);
      }
    }
    // ---- mask + wave-local 64-col stats (identical to original stats reduce) ----
    float msk[4];
#pragma unroll
    for (int n = 0; n < 4; ++n) msk[n] = maskf[b * S_ + s00 + cbase + n * 16 + lr];
#pragma unroll
    for (int m = 0; m < 4; ++m)
#pragma unroll
      for (int n = 0; n < 4; ++n) {
        if (msk[n] != 0.0f) {
#pragma unroll
          for (int i = 0; i < 4; ++i) acc[m][n][i] = -3.4e38f;
        }
      }
    int g = l >> 4;
    int ch = sp * 16 + is * 4 + (w >> 1);  // global 64-chunk index, 0..63
#pragma unroll
    for (int m = 0; m < 4; ++m)
#pragma unroll
      for (int i = 0; i < 4; ++i) {
        float mx = fmaxf(fmaxf(acc[m][0][i], acc[m][1][i]), fmaxf(acc[m][2][i], acc[m][3][i]));
        mx = fmaxf(mx, __shfl_xor(mx, 1));
        mx = fmaxf(mx, __shfl_xor(mx, 2));
        mx = fmaxf(mx, __shfl_xor(mx, 4));
        mx = fmaxf(mx, __shfl_xor(mx, 8));
        float sm = 0.0f;
#pragma unroll
        for (int n = 0; n < 4; ++n) sm += __expf(acc[m][n][i] - mx);
        sm += __shfl_xor(sm, 1);
        sm += __shfl_xor(sm, 2);
        sm += __shfl_xor(sm, 4);
        sm += __shfl_xor(sm, 8);
        if (lr == 0) {
          int gt = t0 + wm + m * 16 + g * 4 + i;
          int r = gt * B_ + b;
          pmax[ch * NROW + r] = mx;
          psum[ch * NROW + r] = sm;
        }
      }
  }
}

// ---------------- finalize: combine 64 chunk partials per row ----------------
__global__ void k_finalize(const float* __restrict__ pmax, const float* __restrict__ psum,
                           float* __restrict__ rmax, float* __restrict__ rsum) {
  int r = blockIdx.x * 256 + threadIdx.x;  // 0..NROW-1
  float mx = -3.4e38f;
#pragma unroll 8
  for (int c = 0; c < 64; ++c) mx = fmaxf(mx, pmax[c * NROW + r]);
  float s = 0.0f;
#pragma unroll 8
  for (int c = 0; c < 64; ++c) s += psum[c * NROW + r] * __expf(pmax[c * NROW + r] - mx);
  rmax[r] = mx;
  rsum[r] = s;
}

// ---------------- OLD fused normalize+comp (fallback path) ----------------
__launch_bounds__(256, 2)
__global__ void k_comp(float* __restrict__ attn, const f16* __restrict__ ctxT,
                       const float* __restrict__ rmax, const float* __restrict__ rsum,
                       const int* __restrict__ allm, float* __restrict__ comp) {
  __shared__ alignas(16) f16 As[2][32 * 64];
  __shared__ alignas(16) f16 Bs[2][256 * 64];
  const int t0 = blockIdx.x * 32;
  const int b = blockIdx.y;
  const int tid = threadIdx.x;
  const int w = tid >> 6, l = tid & 63;
  const int lr = l & 15, hi = l >> 4;
  const int am = allm[b];
  const int ar = tid >> 4;
  const int cg = tid & 15;
  float mx0, mx1, inv0, inv1;
  float* aP0;
  float* aP1;
  {
    int r0 = (t0 + ar) * B_ + b;
    int r1 = (t0 + 16 + ar) * B_ + b;
    mx0 = rmax[r0]; mx1 = rmax[r1];
    inv0 = am ? 0.0f : (1.0f / rsum[r0]);
    inv1 = am ? 0.0f : (1.0f / rsum[r1]);
    aP0 = attn + (size_t)r0 * S_ + cg * 4;
    aP1 = attn + (size_t)r1 * S_ + cg * 4;
  }
  const int aswz = (cg * 8) ^ ((ar & 7) << 4);
  const int bc = tid >> 3;
  const int bs = tid & 7;
  const f16* bP = ctxT + ((size_t)(b * C_ + bc)) * S_ + bs * 8;
  const int bswz = (bs * 16) ^ ((bc & 7) << 4);
  f32x4 acc[2][4] = {};
  f32x4 aC0 = *(const f32x4*)aP0;
  f32x4 aC1 = *(const f32x4*)aP1;
  f16x8 bC[8];
#pragma unroll
  for (int i = 0; i < 8; ++i) bC[i] = *(const f16x8*)(bP + (size_t)i * 32 * S_);
  for (int k = 0; k < S_ / 64; ++k) {
    const int cur = k & 1;
    const int kn = (k + 1) * 64;
    f32x4 aN0 = *(const f32x4*)(aP0 + kn);
    f32x4 aN1 = *(const f32x4*)(aP1 + kn);
    f16x8 bN[8];
#pragma unroll
    for (int i = 0; i < 8; ++i) bN[i] = *(const f16x8*)(bP + (size_t)i * 32 * S_ + kn);
    f32x4 p0, p1;
#pragma unroll
    for (int e = 0; e < 4; ++e) {
      p0[e] = __expf(aC0[e] - mx0) * inv0;
      p1[e] = __expf(aC1[e] - mx1) * inv1;
    }
    *(f32x4*)(aP0 + k * 64) = p0;
    *(f32x4*)(aP1 + k * 64) = p1;
    f16x4 h0, h1;
#pragma unroll
    for (int e = 0; e < 4; ++e) { h0[e] = (f16)p0[e]; h1[e] = (f16)p1[e]; }
    *(f16x4*)((char*)As[cur] + ar * 128 + aswz) = h0;
    *(f16x4*)((char*)As[cur] + (16 + ar) * 128 + aswz) = h1;
#pragma unroll
    for (int i = 0; i < 8; ++i)
      *(f16x8*)((char*)Bs[cur] + (i * 32 + bc) * 128 + bswz) = bC[i];
    asm volatile("s_waitcnt lgkmcnt(0)" ::: "memory");
    __builtin_amdgcn_s_barrier();
    __builtin_amdgcn_sched_barrier(0);
#pragma unroll
    for (int kk = 0; kk < 2; ++kk) {
      const int cb = (kk * 64 + hi * 16) ^ ((lr & 7) << 4);
      f16x8 af[2], bf[4];
#pragma unroll
      for (int m = 0; m < 2; ++m)
        af[m] = *(const f16x8*)((char*)As[cur] + (m * 16 + lr) * 128 + cb);
#pragma unroll
      for (int n = 0; n < 4; ++n)
        bf[n] = *(const f16x8*)((char*)Bs[cur] + (w * 64 + n * 16 + lr) * 128 + cb);
#pragma unroll
      for (int m = 0; m < 2; ++m)
#pragma unroll
        for (int n = 0; n < 4; ++n) acc[m][n] = MFMA(af[m], bf[n], acc[m][n]);
    }
    aC0 = aN0; aC1 = aN1;
#pragma unroll
    for (int i = 0; i < 8; ++i) bC[i] = bN[i];
  }
#pragma unroll
  for (int m = 0; m < 2; ++m)
#pragma unroll
    for (int n = 0; n < 4; ++n)
#pragma unroll
      for (int i = 0; i < 4; ++i) {
        int tl = m * 16 + hi * 4 + i;
        int cc = w * 64 + n * 16 + lr;
        comp[((size_t)(t0 + tl) * B_ + b) * C_ + cc] = acc[m][n][i];
      }
}

// ---------------- pass B v8 (best measured, unchanged): 128-t tile, 512 threads ----------------
__launch_bounds__(512, 1)
__global__ void k_fused4(const f16* __restrict__ qT, const f16* __restrict__ CW,
                         const f16* __restrict__ ctxT, const float* __restrict__ maskf,
                         const float* __restrict__ rmax, const float* __restrict__ rsum,
                         const int* __restrict__ allm,
                         float* __restrict__ attn, float* __restrict__ cptr) {
  __shared__ alignas(16) f16 Qs[128 * 256];    // 64 KB: qT tile, 512B rows, XOR-swizzled
  __shared__ alignas(16) f16 Ps[2][128 * 64];  // 32 KB: P dbuf, 128B rows, XOR-swizzled
  __shared__ float2 Sm[128];                   // (rmax, 1/rsum) per t-row
  const int CH = 32;                           // chunks per block (S/64/2)
  const int bid = blockIdx.x;
  const int b = bid & 7;                       // b==XCD pin
  const int u = bid >> 3;                      // 0..31
  const int t0 = (u & 15) * 128;               // T/128 = 16 t-blocks
  const int sp = u >> 4;                       // 0 or 1
  const int sbase = sp * (S_ / 2);
  const int tid = threadIdx.x;                 // 0..511
  const int w = tid >> 6, l = tid & 63;
  const int lr = l & 15, hi = l >> 4;
  const int rswz = (lr & 7) << 4;
  const int wsg = (w & 3) * 16;   // scores: s-group base of this wave
  const int wtg = (w >> 2) * 4;   // scores: first m-tile of this wave (t = (wtg+m)*16)
  const int srow = wsg + lr;      // lane's s-col within a 64-chunk (scores/P)
  // ---- stage Qs (swizzled) + Sm ----
  {
    const int qr = tid & 127;
    const int cb0 = (tid >> 7) * 128;
    const char* src = (const char*)(qT + ((size_t)(b * T_ + t0 + qr)) * Q_) + cb0;
#pragma unroll
    for (int j = 0; j < 8; ++j) {
      f16x8 v = *(const f16x8*)(src + j * 16);
      *(f16x8*)((char*)Qs + qr * 512 + ((cb0 + j * 16) ^ ((qr & 7) << 4))) = v;
    }
    if (tid < 128) {
      int r = (t0 + tid) * B_ + b;
      float2 sv;
      sv.x = rmax[r];
      sv.y = allm[b] ? 0.0f : (1.0f / rsum[r]);
      Sm[tid] = sv;
    }
  }
  const f16* cwL = CW + ((size_t)b * S_ + sbase + srow) * Q_ + hi * 8;
  const f16* cxL = ctxT + (size_t)(b * C_ + w * 32 + lr) * S_ + sbase + hi * 8;
  const float* maskP = maskf + b * S_ + sbase + srow;
  f32x4 accC[8][2] = {};
  __syncthreads();
  // ---- peeled iter 0: scores(0) only ----
  {
    float mk = maskP[0];
    f32x4 accS[4] = {};
#pragma unroll
    for (int g = 0; g < 2; ++g) {
      f16x8 cw4[4];
#pragma unroll
      for (int j = 0; j < 4; ++j)
        cw4[j] = *(const f16x8*)(cwL + (g * 4 + j) * 32);
#pragma unroll
      for (int j = 0; j < 4; ++j) {
        const int kq = g * 4 + j;
#pragma unroll
        for (int m = 0; m < 4; ++m) {
          f16x8 a = *(const f16x8*)((char*)Qs + ((wtg + m) * 16 + lr) * 512 +
                                    ((kq * 64 + hi * 16) ^ rswz));
          accS[m] = MFMA(a, cw4[j], accS[m]);
        }
      }
    }
#pragma unroll
    for (int m = 0; m < 4; ++m)
#pragma unroll
      for (int i = 0; i < 4; ++i) {
        int tl = (wtg + m) * 16 + hi * 4 + i;
        float2 sv = Sm[tl];
        float p = (mk != 0.0f) ? 0.0f : __expf(accS[m][i] - sv.x) * sv.y;
        float po = __shfl_xor(p, 1);
        if (!(lr & 1)) {
          float2 fp; fp.x = p; fp.y = po;
          *(float2*)&attn[((size_t)(t0 + tl) * B_ + b) * S_ + sbase + srow] = fp;
          f16x2 h; h[0] = (f16)p; h[1] = (f16)po;
          *(f16x2*)((char*)Ps[0] + ((tl * 128 + srow * 2) ^ ((tl & 7) << 4))) = h;
        }
      }
    asm volatile("s_waitcnt lgkmcnt(0)" ::: "memory");
    __builtin_amdgcn_s_barrier();
  }
  // ---- steady: iter k = cx-issue || scores(k) -> normalize(k) -> comp(k-1) ----
  for (int k = 1; k < CH; ++k) {
    const int s0 = k * 64;
    const int sc0 = s0 - 64;
    const int cur = k & 1, prev = cur ^ 1;
    float mk = maskP[s0];
    // issue cx loads first (consumed last, in comp) — cache latency hides under scores
    f16x8 cx4[4];
#pragma unroll
    for (int kk = 0; kk < 2; ++kk)
#pragma unroll
      for (int n = 0; n < 2; ++n)
        cx4[kk * 2 + n] = *(const f16x8*)(cxL + (size_t)(n * 16) * S_ + sc0 + kk * 32);
    // scores(k): cw JIT (grouped 4-wide), af from Qs LDS
    f32x4 accS[4] = {};
#pragma unroll
    for (int g = 0; g < 2; ++g) {
      f16x8 cw4[4];
#pragma unroll
      for (int j = 0; j < 4; ++j)
        cw4[j] = *(const f16x8*)(cwL + (size_t)s0 * Q_ + (g * 4 + j) * 32);
#pragma unroll
      for (int j = 0; j < 4; ++j) {
        const int kq = g * 4 + j;
#pragma unroll
        for (int m = 0; m < 4; ++m) {
          f16x8 a = *(const f16x8*)((char*)Qs + ((wtg + m) * 16 + lr) * 512 +
                                    ((kq * 64 + hi * 16) ^ rswz));
          accS[m] = MFMA(a, cw4[j], accS[m]);
        }
      }
    }
    // normalize(k) -> attn + Ps[cur]  (accS dies before comp needs regs)
#pragma unroll
    for (int m = 0; m < 4; ++m)
#pragma unroll
      for (int i = 0; i < 4; ++i) {
        int tl = (wtg + m) * 16 + hi * 4 + i;
        float2 sv = Sm[tl];
        float p = (mk != 0.0f) ? 0.0f : __expf(accS[m][i] - sv.x) * sv.y;
        float po = __shfl_xor(p, 1);
        if (!(lr & 1)) {
          float2 fp; fp.x = p; fp.y = po;
          *(float2*)&attn[((size_t)(t0 + tl) * B_ + b) * S_ + sbase + s0 + srow] = fp;
          f16x2 h; h[0] = (f16)p; h[1] = (f16)po;
          *(f16x2*)((char*)Ps[cur] + ((tl * 128 + srow * 2) ^ ((tl & 7) << 4))) = h;
        }
      }
    // comp(k-1): pa from Ps[prev] (all 128 t-rows), cx already in flight
#pragma unroll
    for (int kk = 0; kk < 2; ++kk) {
#pragma unroll
      for (int m = 0; m < 8; ++m) {
        f16x8 pa = *(const f16x8*)((char*)Ps[prev] +
                                   (((m * 16 + lr) * 128 + kk * 64 + hi * 16) ^ rswz));
#pragma unroll
        for (int n = 0; n < 2; ++n) accC[m][n] = MFMA(pa, cx4[kk * 2 + n], accC[m][n]);
      }
    }
    // publish Ps[cur] / protect Ps[prev]; vmcnt NOT drained
    asm volatile("s_waitcnt lgkmcnt(0)" ::: "memory");
    __builtin_amdgcn_s_barrier();
  }
  // ---- epilogue: comp(last chunk) ----
  {
    const int sc0 = (CH - 1) * 64;
    const int prev = (CH - 1) & 1;
#pragma unroll
    for (int kk = 0; kk < 2; ++kk) {
      f16x8 cx2[2];
#pragma unroll
      for (int n = 0; n < 2; ++n)
        cx2[n] = *(const f16x8*)(cxL + (size_t)(n * 16) * S_ + sc0 + kk * 32);
#pragma unroll
      for (int m = 0; m < 8; ++m) {
        f16x8 pa = *(const f16x8*)((char*)Ps[prev] +
                                   (((m * 16 + lr) * 128 + kk * 64 + hi * 16) ^ rswz));
#pragma unroll
        for (int n = 0; n < 2; ++n) accC[m][n] = MFMA(pa, cx2[n], accC[m][n]);
      }
    }
  }
  float* cout = cptr + (size_t)sp * T_ * B_ * C_;
#pragma unroll
  for (int m = 0; m < 8; ++m)
#pragma unroll
    for (int n = 0; n < 2; ++n)
#pragma unroll
      for (int i = 0; i < 4; ++i) {
        int tl = m * 16 + hi * 4 + i;
        int cc = w * 32 + n * 16 + lr;
        cout[((size_t)(t0 + tl) * B_ + b) * C_ + cc] = accC[m][n][i];
      }
}

// ---------------- reduce SP=2 comp partials into out ----------------
__global__ void k_comp_red(const float* __restrict__ P, float* __restrict__ comp) {
  size_t i = ((size_t)blockIdx.x * 256 + threadIdx.x) * 4;
  f32x4 a = *(const f32x4*)(P + i);
  f32x4 c = *(const f32x4*)(P + (size_t)T_ * B_ * C_ + i);
  f32x4 r;
#pragma unroll
  for (int e = 0; e < 4; ++e) r[e] = a[e] + c[e];
  *(f32x4*)(comp + i) = r;
}

// ---------------- launch ----------------
extern "C" void kernel_launch(void* const* d_in, const int* in_sizes, int n_in,
                              void* d_out, int out_size, void* d_ws, size_t ws_size,
                              hipStream_t stream) {
  const float* ctx = (const float*)d_in[0];
  const float* query = (const float*)d_in[1];
  const void* mask = d_in[2];
  const float* W = (const float*)d_in[3];

  float* out = (float*)d_out;
  float* attn = out;                               // [T][B][S] f32
  float* comp = out + (size_t)T_ * B_ * S_;        // [T][B][C] f32

  char* ws = (char*)d_ws;
  f16* ctxT = (f16*)(ws);                          // 16,777,216 B
  f16* qT = (f16*)(ws + 16777216);                 //  8,388,608 B
  f16* WT = (f16*)(ws + 25165824);                 //    131,072 B
  float* maskf = (float*)(ws + 25296896);          //    131,072 B
  float* rmax = (float*)(ws + 25427968);           //     65,536 B
  float* rsum = (float*)(ws + 25493504);           //     65,536 B
  int* allm = (int*)(ws + 25559040);
  int* mode = (int*)(ws + 25559072);
  float* pmax = (float*)(ws + 25559168);           //  4,194,304 B
  float* psum = (float*)(ws + 29753472);           //  4,194,304 B -> end 33,947,776

  // common preprocessing
  k_mask_mode<<<1, 256, 0, stream>>>((const unsigned char*)mask, mode, allm);
  k_expand_mask<<<(B_ * S_) / 256, 256, 0, stream>>>(mask, mode, maskf, allm);
  k_conv_w<<<(C_ * Q_) / 256, 256, 0, stream>>>(W, WT);
  k_conv_q<<<(T_ * B_ * Q_ / 4) / 256, 256, 0, stream>>>(query, qT);
  k_transpose_ctx<<<dim3(S_ / 64, C_ / 64, B_), 256, 0, stream>>>(ctx, ctxT);

  if (ws_size >= (size_t)84279424) {
    // NEW path: CW in ws + SP=2 comp partials in ws
    f16* CW2 = (f16*)(ws + 33947776);              // 16,777,216 B -> end 50,724,992
    float* compP = (float*)(ws + 50724992);        // 33,554,432 B -> end 84,279,424
    k_gemm_cw<<<dim3(Q_ / 128, (B_ * S_) / 128), 256, 0, stream>>>(ctx, WT, CW2);
    k_stats6<<<dim3(512), 512, 0, stream>>>(qT, CW2, maskf, pmax, psum);
    k_finalize<<<NROW / 256, 256, 0, stream>>>(pmax, psum, rmax, rsum);
    k_fused4<<<dim3((T_ / 128) * B_ * 2), 512, 0, stream>>>(qT, CW2, ctxT, maskf, rmax, rsum,
                                                            allm, attn, compP);
    k_comp_red<<<(T_ * B_ * C_ / 4) / 256, 256, 0, stream>>>(compP, comp);
  } else {
    // FALLBACK: proven old path (CW aliases comp region; raw scores round-trip via attn)
    f16* CW = (f16*)comp;
    k_gemm_cw<<<dim3(Q_ / 128, (B_ * S_) / 128), 256, 0, stream>>>(ctx, WT, CW);
    k_gemm_scores<<<dim3(S_ / 128, T_ / 128, B_), 256, 0, stream>>>(qT, CW, maskf, attn, pmax, psum);
    k_finalize<<<NROW / 256, 256, 0, stream>>>(pmax, psum, rmax, rsum);
    k_comp<<<dim3(T_ / 32, B_), 256, 0, stream>>>(attn, ctxT, rmax, rsum, allm, comp);
  }
}

// Round 14
// 502.454 us; speedup vs baseline: 1.0993x; 1.0993x over previous
//
#include <hip/hip_runtime.h>

#define B_ 8
#define S_ 4096
#define T_ 2048
#define C_ 256
#define Q_ 256
#define NROW (T_ * B_)

typedef _Float16 f16;
typedef _Float16 f16x8 __attribute__((ext_vector_type(8)));
typedef _Float16 f16x4 __attribute__((ext_vector_type(4)));
typedef _Float16 f16x2 __attribute__((ext_vector_type(2)));
typedef float f32x4 __attribute__((ext_vector_type(4)));

#define MFMA(a, b, c) __builtin_amdgcn_mfma_f32_16x16x32_f16((a), (b), (c), 0, 0, 0)

// ---------------- mask dtype sniff (device-side, deterministic) ----------------
// mode: 0 = int32, 1 = bytes (bool/uint8), 2 = float32, 3 = all-zero (no mask)
__global__ void k_mask_mode(const unsigned char* __restrict__ mb, int* __restrict__ mode,
                            int* __restrict__ allm) {
  __shared__ int s0_, s123_;
  if (threadIdx.x == 0) { s0_ = 0; s123_ = 0; }
  __syncthreads();
  int a0 = 0, a123 = 0;
  int base = threadIdx.x * 128;
  for (int i = 0; i < 128; ++i) {
    int idx = base + i;
    int v = mb[idx];
    if (idx & 3) a123 |= v; else a0 |= v;
  }
  if (a0) atomicOr(&s0_, 1);
  if (a123) atomicOr(&s123_, 1);
  __syncthreads();
  if (threadIdx.x == 0) {
    int m;
    if (s123_ == 0 && s0_ == 0) m = 3;
    else if (s123_ == 0) m = 0;
    else if (s0_ == 0) m = 2;
    else m = 1;
    *mode = m;
  }
  if (threadIdx.x < B_) allm[threadIdx.x] = 1;
}

__global__ void k_expand_mask(const void* __restrict__ mp, const int* __restrict__ mode,
                              float* __restrict__ maskf, int* __restrict__ allm) {
  int i = blockIdx.x * 256 + threadIdx.x;  // B_*S_ total
  int md = *mode;
  int m;
  if (md == 0)      m = ((const int*)mp)[i] != 0;
  else if (md == 1) m = ((const unsigned char*)mp)[i] != 0;
  else if (md == 2) m = ((const float*)mp)[i] != 0.0f;
  else              m = 0;
  maskf[i] = m ? 1.0f : 0.0f;
  if (!m) atomicAnd(&allm[i / S_], 0);
}

// ---------------- conversions ----------------
__global__ void k_conv_w(const float* __restrict__ W, f16* __restrict__ WT) {
  int i = blockIdx.x * 256 + threadIdx.x;  // C_*Q_
  int c = i >> 8, q = i & 255;
  WT[q * C_ + c] = (f16)W[i];
}

__global__ void k_conv_q(const float* __restrict__ q, f16* __restrict__ qT) {
  int i = blockIdx.x * 256 + threadIdx.x;  // T_*B_*Q_/4 threads
  int e = i * 4;
  int t = e / (B_ * Q_);
  int rb = e - t * (B_ * Q_);
  int b = rb >> 8;
  int qq = rb & 255;
  f32x4 v = *(const f32x4*)(q + e);
  f16x4 h; h[0] = (f16)v[0]; h[1] = (f16)v[1]; h[2] = (f16)v[2]; h[3] = (f16)v[3];
  *(f16x4*)(qT + ((size_t)(b * T_ + t)) * Q_ + qq) = h;
}

// ctx [b][s][c] f32 -> ctxT [b][c][s] f16, 64x64 tiles via LDS
__global__ void k_transpose_ctx(const float* __restrict__ ctx, f16* __restrict__ ctxT) {
  __shared__ f16 tile[64][65];
  int s0 = blockIdx.x * 64, c0 = blockIdx.y * 64, b = blockIdx.z;
  int r = threadIdx.x >> 2;
  int cs = (threadIdx.x & 3) * 16;
  const float* src = ctx + ((size_t)(b * S_ + s0 + r)) * C_ + c0 + cs;
  f32x4 v0 = ((const f32x4*)src)[0];
  f32x4 v1 = ((const f32x4*)src)[1];
  f32x4 v2 = ((const f32x4*)src)[2];
  f32x4 v3 = ((const f32x4*)src)[3];
#pragma unroll
  for (int j = 0; j < 4; ++j) {
    tile[r][cs + j] = (f16)v0[j];
    tile[r][cs + 4 + j] = (f16)v1[j];
    tile[r][cs + 8 + j] = (f16)v2[j];
    tile[r][cs + 12 + j] = (f16)v3[j];
  }
  __syncthreads();
  int c = threadIdx.x >> 2;
  int ss = (threadIdx.x & 3) * 16;
  f16x8 o0, o1;
#pragma unroll
  for (int j = 0; j < 8; ++j) { o0[j] = tile[ss + j][c]; o1[j] = tile[ss + 8 + j][c]; }
  f16* dst = ctxT + ((size_t)(b * C_ + c0 + c)) * S_ + s0 + ss;
  *(f16x8*)dst = o0;
  *(f16x8*)(dst + 8) = o1;
}

// ---------------- GEMM 1: CW[m=(b,s)][q] = ctx @ W^T, scaled 1/16, f16 out ----------------
__launch_bounds__(256, 2)
__global__ void k_gemm_cw(const float* __restrict__ ctx, const f16* __restrict__ WT,
                          f16* __restrict__ CW) {
  __shared__ alignas(16) f16 As[128 * 32];
  __shared__ alignas(16) f16 Bs[128 * 32];
  int n0 = blockIdx.x * 128;  // q
  int m0 = blockIdx.y * 128;  // flat (b,s)
  int tid = threadIdx.x;
  int w = tid >> 6, l = tid & 63;
  int wm = (w >> 1) * 64, wn = (w & 1) * 64;
  int lr = l & 15, lk = (l >> 4) * 8;
  f32x4 acc[4][4] = {};
  for (int k0 = 0; k0 < C_; k0 += 32) {
    __syncthreads();
#pragma unroll
    for (int it = 0; it < 2; ++it) {
      int h = (it * 256 + tid) * 8;
      int row = h >> 5, kk = h & 31;
      const float* ap = ctx + (size_t)(m0 + row) * C_ + k0 + kk;
      f32x4 x0 = ((const f32x4*)ap)[0];
      f32x4 x1 = ((const f32x4*)ap)[1];
      f16x8 hv;
#pragma unroll
      for (int j = 0; j < 4; ++j) { hv[j] = (f16)x0[j]; hv[4 + j] = (f16)x1[j]; }
      *(f16x8*)&As[row * 32 + kk] = hv;
    }
#pragma unroll
    for (int it = 0; it < 2; ++it) {
      int h = (it * 256 + tid) * 8;
      int row = h >> 5, kk = h & 31;
      *(f16x8*)&Bs[row * 32 + kk] = *(const f16x8*)&WT[(size_t)(n0 + row) * C_ + k0 + kk];
    }
    __syncthreads();
    f16x8 af[4], bf[4];
#pragma unroll
    for (int m = 0; m < 4; ++m) af[m] = *(const f16x8*)&As[(wm + m * 16 + lr) * 32 + lk];
#pragma unroll
    for (int n = 0; n < 4; ++n) bf[n] = *(const f16x8*)&Bs[(wn + n * 16 + lr) * 32 + lk];
#pragma unroll
    for (int m = 0; m < 4; ++m)
#pragma unroll
      for (int n = 0; n < 4; ++n) acc[m][n] = MFMA(af[m], bf[n], acc[m][n]);
  }
#pragma unroll
  for (int m = 0; m < 4; ++m)
#pragma unroll
    for (int n = 0; n < 4; ++n)
#pragma unroll
      for (int i = 0; i < 4; ++i) {
        int gm = m0 + wm + m * 16 + (l >> 4) * 4 + i;
        int gn = n0 + wn + n * 16 + lr;
        CW[(size_t)gm * Q_ + gn] = (f16)(acc[m][n][i] * 0.0625f);
      }
}

// ---------------- OLD GEMM 2 (fallback path): scores + raw attn store + stats ----------------
__launch_bounds__(256, 2)
__global__ void k_gemm_scores(const f16* __restrict__ qT, const f16* __restrict__ CW,
                              const float* __restrict__ maskf, float* __restrict__ attn,
                              float* __restrict__ pmax, float* __restrict__ psum) {
  __shared__ alignas(16) f16 As[128 * 32];
  __shared__ alignas(16) f16 Bs[128 * 32];
  int n0 = blockIdx.x * 128;  // s
  int m0 = blockIdx.y * 128;  // t
  int b = blockIdx.z;
  const f16* A = qT + (size_t)b * T_ * Q_;
  const f16* Bm = CW + (size_t)b * S_ * Q_;
  int tid = threadIdx.x;
  int w = tid >> 6, l = tid & 63;
  int wm = (w >> 1) * 64, wn = (w & 1) * 64;
  int lr = l & 15, lk = (l >> 4) * 8;
  f32x4 acc[4][4] = {};
  for (int k0 = 0; k0 < Q_; k0 += 32) {
    __syncthreads();
#pragma unroll
    for (int it = 0; it < 2; ++it) {
      int h = (it * 256 + tid) * 8;
      int row = h >> 5, kk = h & 31;
      *(f16x8*)&As[row * 32 + kk] = *(const f16x8*)&A[(size_t)(m0 + row) * Q_ + k0 + kk];
    }
#pragma unroll
    for (int it = 0; it < 2; ++it) {
      int h = (it * 256 + tid) * 8;
      int row = h >> 5, kk = h & 31;
      *(f16x8*)&Bs[row * 32 + kk] = *(const f16x8*)&Bm[(size_t)(n0 + row) * Q_ + k0 + kk];
    }
    __syncthreads();
    f16x8 af[4], bf[4];
#pragma unroll
    for (int m = 0; m < 4; ++m) af[m] = *(const f16x8*)&As[(wm + m * 16 + lr) * 32 + lk];
#pragma unroll
    for (int n = 0; n < 4; ++n) bf[n] = *(const f16x8*)&Bs[(wn + n * 16 + lr) * 32 + lk];
#pragma unroll
    for (int m = 0; m < 4; ++m)
#pragma unroll
      for (int n = 0; n < 4; ++n) acc[m][n] = MFMA(af[m], bf[n], acc[m][n]);
  }
  float msk[4];
#pragma unroll
  for (int n = 0; n < 4; ++n) msk[n] = maskf[b * S_ + n0 + wn + n * 16 + lr];
#pragma unroll
  for (int m = 0; m < 4; ++m)
#pragma unroll
    for (int n = 0; n < 4; ++n) {
      int gn = n0 + wn + n * 16 + lr;
#pragma unroll
      for (int i = 0; i < 4; ++i) {
        int gt = m0 + wm + m * 16 + (l >> 4) * 4 + i;
        float v = acc[m][n][i];
        if (msk[n] != 0.0f) v = -3.4e38f;
        acc[m][n][i] = v;
        attn[((size_t)gt * B_ + b) * S_ + gn] = v;
      }
    }
  int g = l >> 4;
  int ch = blockIdx.x * 2 + (w & 1);
#pragma unroll
  for (int m = 0; m < 4; ++m)
#pragma unroll
    for (int i = 0; i < 4; ++i) {
      float mx = fmaxf(fmaxf(acc[m][0][i], acc[m][1][i]), fmaxf(acc[m][2][i], acc[m][3][i]));
      mx = fmaxf(mx, __shfl_xor(mx, 1));
      mx = fmaxf(mx, __shfl_xor(mx, 2));
      mx = fmaxf(mx, __shfl_xor(mx, 4));
      mx = fmaxf(mx, __shfl_xor(mx, 8));
      float sm = 0.0f;
#pragma unroll
      for (int n = 0; n < 4; ++n) sm += __expf(acc[m][n][i] - mx);
      sm += __shfl_xor(sm, 1);
      sm += __shfl_xor(sm, 2);
      sm += __shfl_xor(sm, 4);
      sm += __shfl_xor(sm, 8);
      if (lr == 0) {
        int gt = m0 + wm + m * 16 + g * 4 + i;
        int r = gt * B_ + b;
        pmax[ch * NROW + r] = mx;
        psum[ch * NROW + r] = sm;
      }
    }
}

// ---------------- pass A v5 (best measured): 128^2 stats tile + k_comp pipeline ----------------
// Register-prefetch next K-step's panels while computing current, double-buffered LDS,
// ONE lgkm-only barrier per step, vmcnt never drained; XCD pin. Accumulation chain
// identical to the original stats (8 ascending K-steps, same MFMA order).
__launch_bounds__(256, 2)
__global__ void k_stats5(const f16* __restrict__ qT, const f16* __restrict__ CW,
                         const float* __restrict__ maskf,
                         float* __restrict__ pmax, float* __restrict__ psum) {
  __shared__ alignas(16) f16 As[2][128 * 32];
  __shared__ alignas(16) f16 Bs[2][128 * 32];
  const int bid = blockIdx.x;
  const int b = bid & 7;           // XCD pin: batch panels stay in local L2/L3 slice
  const int u = bid >> 3;          // 0..511
  const int sblk = u & 31;         // 32 s-blocks
  const int tblk = u >> 5;         // 16 t-blocks
  const int n0 = sblk * 128, m0 = tblk * 128;
  const f16* A = qT + (size_t)b * T_ * Q_;
  const f16* Bm = CW + (size_t)b * S_ * Q_;
  const int tid = threadIdx.x;
  const int w = tid >> 6, l = tid & 63;
  const int wm = (w >> 1) * 64, wn = (w & 1) * 64;
  const int lr = l & 15, lk = (l >> 4) * 8;
  // staging map: thread -> rows {r0, 64+r0}, 16B at col kc
  const int r0 = tid >> 2;         // 0..63
  const int kc = (tid & 3) * 8;    // f16 col 0/8/16/24
  const f16* aP0 = A + (size_t)(m0 + r0) * Q_ + kc;
  const f16* aP1 = A + (size_t)(m0 + 64 + r0) * Q_ + kc;
  const f16* bP0 = Bm + (size_t)(n0 + r0) * Q_ + kc;
  const f16* bP1 = Bm + (size_t)(n0 + 64 + r0) * Q_ + kc;
  f32x4 acc[4][4] = {};
  // prologue: K-step 0 into registers
  f16x8 aR0 = *(const f16x8*)aP0;
  f16x8 aR1 = *(const f16x8*)aP1;
  f16x8 bR0 = *(const f16x8*)bP0;
  f16x8 bR1 = *(const f16x8*)bP1;
  for (int ks = 0; ks < 8; ++ks) {
    const int cur = ks & 1;
    // stage current regs -> LDS[cur]
    *(f16x8*)&As[cur][r0 * 32 + kc] = aR0;
    *(f16x8*)&As[cur][(64 + r0) * 32 + kc] = aR1;
    *(f16x8*)&Bs[cur][r0 * 32 + kc] = bR0;
    *(f16x8*)&Bs[cur][(64 + r0) * 32 + kc] = bR1;
    // prefetch next K-step (consumed next iter -> full iteration of latency cover)
    if (ks < 7) {
      const int k0 = (ks + 1) * 32;
      aR0 = *(const f16x8*)(aP0 + k0);
      aR1 = *(const f16x8*)(aP1 + k0);
      bR0 = *(const f16x8*)(bP0 + k0);
      bR1 = *(const f16x8*)(bP1 + k0);
    }
    // publish LDS[cur]; vmcnt NOT drained (prefetch stays in flight)
    asm volatile("s_waitcnt lgkmcnt(0)" ::: "memory");
    __builtin_amdgcn_s_barrier();
    __builtin_amdgcn_sched_barrier(0);
    f16x8 af[4], bf[4];
#pragma unroll
    for (int m = 0; m < 4; ++m) af[m] = *(const f16x8*)&As[cur][(wm + m * 16 + lr) * 32 + lk];
#pragma unroll
    for (int n = 0; n < 4; ++n) bf[n] = *(const f16x8*)&Bs[cur][(wn + n * 16 + lr) * 32 + lk];
#pragma unroll
    for (int m = 0; m < 4; ++m)
#pragma unroll
      for (int n = 0; n < 4; ++n) acc[m][n] = MFMA(af[m], bf[n], acc[m][n]);
  }
  // ---- mask + per-chunk stats (identical to old stats) ----
  float msk[4];
#pragma unroll
  for (int n = 0; n < 4; ++n) msk[n] = maskf[b * S_ + n0 + wn + n * 16 + lr];
#pragma unroll
  for (int m = 0; m < 4; ++m)
#pragma unroll
    for (int n = 0; n < 4; ++n) {
      if (msk[n] != 0.0f) {
#pragma unroll
        for (int i = 0; i < 4; ++i) acc[m][n][i] = -3.4e38f;
      }
    }
  int g = l >> 4;
  int ch = sblk * 2 + (w & 1);
#pragma unroll
  for (int m = 0; m < 4; ++m)
#pragma unroll
    for (int i = 0; i < 4; ++i) {
      float mx = fmaxf(fmaxf(acc[m][0][i], acc[m][1][i]), fmaxf(acc[m][2][i], acc[m][3][i]));
      mx = fmaxf(mx, __shfl_xor(mx, 1));
      mx = fmaxf(mx, __shfl_xor(mx, 2));
      mx = fmaxf(mx, __shfl_xor(mx, 4));
      mx = fmaxf(mx, __shfl_xor(mx, 8));
      float sm = 0.0f;
#pragma unroll
      for (int n = 0; n < 4; ++n) sm += __expf(acc[m][n][i] - mx);
      sm += __shfl_xor(sm, 1);
      sm += __shfl_xor(sm, 2);
      sm += __shfl_xor(sm, 4);
      sm += __shfl_xor(sm, 8);
      if (lr == 0) {
        int gt = m0 + wm + m * 16 + g * 4 + i;
        int r = gt * B_ + b;
        pmax[ch * NROW + r] = mx;
        psum[ch * NROW + r] = sm;
      }
    }
}

// ---------------- finalize: combine 64 chunk partials per row ----------------
__global__ void k_finalize(const float* __restrict__ pmax, const float* __restrict__ psum,
                           float* __restrict__ rmax, float* __restrict__ rsum) {
  int r = blockIdx.x * 256 + threadIdx.x;  // 0..NROW-1
  float mx = -3.4e38f;
#pragma unroll 8
  for (int c = 0; c < 64; ++c) mx = fmaxf(mx, pmax[c * NROW + r]);
  float s = 0.0f;
#pragma unroll 8
  for (int c = 0; c < 64; ++c) s += psum[c * NROW + r] * __expf(pmax[c * NROW + r] - mx);
  rmax[r] = mx;
  rsum[r] = s;
}

// ---------------- OLD fused normalize+comp (fallback path) ----------------
__launch_bounds__(256, 2)
__global__ void k_comp(float* __restrict__ attn, const f16* __restrict__ ctxT,
                       const float* __restrict__ rmax, const float* __restrict__ rsum,
                       const int* __restrict__ allm, float* __restrict__ comp) {
  __shared__ alignas(16) f16 As[2][32 * 64];
  __shared__ alignas(16) f16 Bs[2][256 * 64];
  const int t0 = blockIdx.x * 32;
  const int b = blockIdx.y;
  const int tid = threadIdx.x;
  const int w = tid >> 6, l = tid & 63;
  const int lr = l & 15, hi = l >> 4;
  const int am = allm[b];
  const int ar = tid >> 4;
  const int cg = tid & 15;
  float mx0, mx1, inv0, inv1;
  float* aP0;
  float* aP1;
  {
    int r0 = (t0 + ar) * B_ + b;
    int r1 = (t0 + 16 + ar) * B_ + b;
    mx0 = rmax[r0]; mx1 = rmax[r1];
    inv0 = am ? 0.0f : (1.0f / rsum[r0]);
    inv1 = am ? 0.0f : (1.0f / rsum[r1]);
    aP0 = attn + (size_t)r0 * S_ + cg * 4;
    aP1 = attn + (size_t)r1 * S_ + cg * 4;
  }
  const int aswz = (cg * 8) ^ ((ar & 7) << 4);
  const int bc = tid >> 3;
  const int bs = tid & 7;
  const f16* bP = ctxT + ((size_t)(b * C_ + bc)) * S_ + bs * 8;
  const int bswz = (bs * 16) ^ ((bc & 7) << 4);
  f32x4 acc[2][4] = {};
  f32x4 aC0 = *(const f32x4*)aP0;
  f32x4 aC1 = *(const f32x4*)aP1;
  f16x8 bC[8];
#pragma unroll
  for (int i = 0; i < 8; ++i) bC[i] = *(const f16x8*)(bP + (size_t)i * 32 * S_);
  for (int k = 0; k < S_ / 64; ++k) {
    const int cur = k & 1;
    const int kn = (k + 1) * 64;
    f32x4 aN0 = *(const f32x4*)(aP0 + kn);
    f32x4 aN1 = *(const f32x4*)(aP1 + kn);
    f16x8 bN[8];
#pragma unroll
    for (int i = 0; i < 8; ++i) bN[i] = *(const f16x8*)(bP + (size_t)i * 32 * S_ + kn);
    f32x4 p0, p1;
#pragma unroll
    for (int e = 0; e < 4; ++e) {
      p0[e] = __expf(aC0[e] - mx0) * inv0;
      p1[e] = __expf(aC1[e] - mx1) * inv1;
    }
    *(f32x4*)(aP0 + k * 64) = p0;
    *(f32x4*)(aP1 + k * 64) = p1;
    f16x4 h0, h1;
#pragma unroll
    for (int e = 0; e < 4; ++e) { h0[e] = (f16)p0[e]; h1[e] = (f16)p1[e]; }
    *(f16x4*)((char*)As[cur] + ar * 128 + aswz) = h0;
    *(f16x4*)((char*)As[cur] + (16 + ar) * 128 + aswz) = h1;
#pragma unroll
    for (int i = 0; i < 8; ++i)
      *(f16x8*)((char*)Bs[cur] + (i * 32 + bc) * 128 + bswz) = bC[i];
    asm volatile("s_waitcnt lgkmcnt(0)" ::: "memory");
    __builtin_amdgcn_s_barrier();
    __builtin_amdgcn_sched_barrier(0);
#pragma unroll
    for (int kk = 0; kk < 2; ++kk) {
      const int cb = (kk * 64 + hi * 16) ^ ((lr & 7) << 4);
      f16x8 af[2], bf[4];
#pragma unroll
      for (int m = 0; m < 2; ++m)
        af[m] = *(const f16x8*)((char*)As[cur] + (m * 16 + lr) * 128 + cb);
#pragma unroll
      for (int n = 0; n < 4; ++n)
        bf[n] = *(const f16x8*)((char*)Bs[cur] + (w * 64 + n * 16 + lr) * 128 + cb);
#pragma unroll
      for (int m = 0; m < 2; ++m)
#pragma unroll
        for (int n = 0; n < 4; ++n) acc[m][n] = MFMA(af[m], bf[n], acc[m][n]);
    }
    aC0 = aN0; aC1 = aN1;
#pragma unroll
    for (int i = 0; i < 8; ++i) bC[i] = bN[i];
  }
#pragma unroll
  for (int m = 0; m < 2; ++m)
#pragma unroll
    for (int n = 0; n < 4; ++n)
#pragma unroll
      for (int i = 0; i < 4; ++i) {
        int tl = m * 16 + hi * 4 + i;
        int cc = w * 64 + n * 16 + lr;
        comp[((size_t)(t0 + tl) * B_ + b) * C_ + cc] = acc[m][n][i];
      }
}

// ---------------- pass B v8 (best measured, unchanged): 128-t tile, 512 threads ----------------
__launch_bounds__(512, 1)
__global__ void k_fused4(const f16* __restrict__ qT, const f16* __restrict__ CW,
                         const f16* __restrict__ ctxT, const float* __restrict__ maskf,
                         const float* __restrict__ rmax, const float* __restrict__ rsum,
                         const int* __restrict__ allm,
                         float* __restrict__ attn, float* __restrict__ cptr) {
  __shared__ alignas(16) f16 Qs[128 * 256];    // 64 KB: qT tile, 512B rows, XOR-swizzled
  __shared__ alignas(16) f16 Ps[2][128 * 64];  // 32 KB: P dbuf, 128B rows, XOR-swizzled
  __shared__ float2 Sm[128];                   // (rmax, 1/rsum) per t-row
  const int CH = 32;                           // chunks per block (S/64/2)
  const int bid = blockIdx.x;
  const int b = bid & 7;                       // b==XCD pin
  const int u = bid >> 3;                      // 0..31
  const int t0 = (u & 15) * 128;               // T/128 = 16 t-blocks
  const int sp = u >> 4;                       // 0 or 1
  const int sbase = sp * (S_ / 2);
  const int tid = threadIdx.x;                 // 0..511
  const int w = tid >> 6, l = tid & 63;
  const int lr = l & 15, hi = l >> 4;
  const int rswz = (lr & 7) << 4;
  const int wsg = (w & 3) * 16;   // scores: s-group base of this wave
  const int wtg = (w >> 2) * 4;   // scores: first m-tile of this wave (t = (wtg+m)*16)
  const int srow = wsg + lr;      // lane's s-col within a 64-chunk (scores/P)
  // ---- stage Qs (swizzled) + Sm ----
  {
    const int qr = tid & 127;
    const int cb0 = (tid >> 7) * 128;
    const char* src = (const char*)(qT + ((size_t)(b * T_ + t0 + qr)) * Q_) + cb0;
#pragma unroll
    for (int j = 0; j < 8; ++j) {
      f16x8 v = *(const f16x8*)(src + j * 16);
      *(f16x8*)((char*)Qs + qr * 512 + ((cb0 + j * 16) ^ ((qr & 7) << 4))) = v;
    }
    if (tid < 128) {
      int r = (t0 + tid) * B_ + b;
      float2 sv;
      sv.x = rmax[r];
      sv.y = allm[b] ? 0.0f : (1.0f / rsum[r]);
      Sm[tid] = sv;
    }
  }
  const f16* cwL = CW + ((size_t)b * S_ + sbase + srow) * Q_ + hi * 8;
  const f16* cxL = ctxT + (size_t)(b * C_ + w * 32 + lr) * S_ + sbase + hi * 8;
  const float* maskP = maskf + b * S_ + sbase + srow;
  f32x4 accC[8][2] = {};
  __syncthreads();
  // ---- peeled iter 0: scores(0) only ----
  {
    float mk = maskP[0];
    f32x4 accS[4] = {};
#pragma unroll
    for (int g = 0; g < 2; ++g) {
      f16x8 cw4[4];
#pragma unroll
      for (int j = 0; j < 4; ++j)
        cw4[j] = *(const f16x8*)(cwL + (g * 4 + j) * 32);
#pragma unroll
      for (int j = 0; j < 4; ++j) {
        const int kq = g * 4 + j;
#pragma unroll
        for (int m = 0; m < 4; ++m) {
          f16x8 a = *(const f16x8*)((char*)Qs + ((wtg + m) * 16 + lr) * 512 +
                                    ((kq * 64 + hi * 16) ^ rswz));
          accS[m] = MFMA(a, cw4[j], accS[m]);
        }
      }
    }
#pragma unroll
    for (int m = 0; m < 4; ++m)
#pragma unroll
      for (int i = 0; i < 4; ++i) {
        int tl = (wtg + m) * 16 + hi * 4 + i;
        float2 sv = Sm[tl];
        float p = (mk != 0.0f) ? 0.0f : __expf(accS[m][i] - sv.x) * sv.y;
        float po = __shfl_xor(p, 1);
        if (!(lr & 1)) {
          float2 fp; fp.x = p; fp.y = po;
          *(float2*)&attn[((size_t)(t0 + tl) * B_ + b) * S_ + sbase + srow] = fp;
          f16x2 h; h[0] = (f16)p; h[1] = (f16)po;
          *(f16x2*)((char*)Ps[0] + ((tl * 128 + srow * 2) ^ ((tl & 7) << 4))) = h;
        }
      }
    asm volatile("s_waitcnt lgkmcnt(0)" ::: "memory");
    __builtin_amdgcn_s_barrier();
  }
  // ---- steady: iter k = cx-issue || scores(k) -> normalize(k) -> comp(k-1) ----
  for (int k = 1; k < CH; ++k) {
    const int s0 = k * 64;
    const int sc0 = s0 - 64;
    const int cur = k & 1, prev = cur ^ 1;
    float mk = maskP[s0];
    // issue cx loads first (consumed last, in comp) — cache latency hides under scores
    f16x8 cx4[4];
#pragma unroll
    for (int kk = 0; kk < 2; ++kk)
#pragma unroll
      for (int n = 0; n < 2; ++n)
        cx4[kk * 2 + n] = *(const f16x8*)(cxL + (size_t)(n * 16) * S_ + sc0 + kk * 32);
    // scores(k): cw JIT (grouped 4-wide), af from Qs LDS
    f32x4 accS[4] = {};
#pragma unroll
    for (int g = 0; g < 2; ++g) {
      f16x8 cw4[4];
#pragma unroll
      for (int j = 0; j < 4; ++j)
        cw4[j] = *(const f16x8*)(cwL + (size_t)s0 * Q_ + (g * 4 + j) * 32);
#pragma unroll
      for (int j = 0; j < 4; ++j) {
        const int kq = g * 4 + j;
#pragma unroll
        for (int m = 0; m < 4; ++m) {
          f16x8 a = *(const f16x8*)((char*)Qs + ((wtg + m) * 16 + lr) * 512 +
                                    ((kq * 64 + hi * 16) ^ rswz));
          accS[m] = MFMA(a, cw4[j], accS[m]);
        }
      }
    }
    // normalize(k) -> attn + Ps[cur]  (accS dies before comp needs regs)
#pragma unroll
    for (int m = 0; m < 4; ++m)
#pragma unroll
      for (int i = 0; i < 4; ++i) {
        int tl = (wtg + m) * 16 + hi * 4 + i;
        float2 sv = Sm[tl];
        float p = (mk != 0.0f) ? 0.0f : __expf(accS[m][i] - sv.x) * sv.y;
        float po = __shfl_xor(p, 1);
        if (!(lr & 1)) {
          float2 fp; fp.x = p; fp.y = po;
          *(float2*)&attn[((size_t)(t0 + tl) * B_ + b) * S_ + sbase + s0 + srow] = fp;
          f16x2 h; h[0] = (f16)p; h[1] = (f16)po;
          *(f16x2*)((char*)Ps[cur] + ((tl * 128 + srow * 2) ^ ((tl & 7) << 4))) = h;
        }
      }
    // comp(k-1): pa from Ps[prev] (all 128 t-rows), cx already in flight
#pragma unroll
    for (int kk = 0; kk < 2; ++kk) {
#pragma unroll
      for (int m = 0; m < 8; ++m) {
        f16x8 pa = *(const f16x8*)((char*)Ps[prev] +
                                   (((m * 16 + lr) * 128 + kk * 64 + hi * 16) ^ rswz));
#pragma unroll
        for (int n = 0; n < 2; ++n) accC[m][n] = MFMA(pa, cx4[kk * 2 + n], accC[m][n]);
      }
    }
    // publish Ps[cur] / protect Ps[prev]; vmcnt NOT drained
    asm volatile("s_waitcnt lgkmcnt(0)" ::: "memory");
    __builtin_amdgcn_s_barrier();
  }
  // ---- epilogue: comp(last chunk) ----
  {
    const int sc0 = (CH - 1) * 64;
    const int prev = (CH - 1) & 1;
#pragma unroll
    for (int kk = 0; kk < 2; ++kk) {
      f16x8 cx2[2];
#pragma unroll
      for (int n = 0; n < 2; ++n)
        cx2[n] = *(const f16x8*)(cxL + (size_t)(n * 16) * S_ + sc0 + kk * 32);
#pragma unroll
      for (int m = 0; m < 8; ++m) {
        f16x8 pa = *(const f16x8*)((char*)Ps[prev] +
                                   (((m * 16 + lr) * 128 + kk * 64 + hi * 16) ^ rswz));
#pragma unroll
        for (int n = 0; n < 2; ++n) accC[m][n] = MFMA(pa, cx2[n], accC[m][n]);
      }
    }
  }
  float* cout = cptr + (size_t)sp * T_ * B_ * C_;
#pragma unroll
  for (int m = 0; m < 8; ++m)
#pragma unroll
    for (int n = 0; n < 2; ++n)
#pragma unroll
      for (int i = 0; i < 4; ++i) {
        int tl = m * 16 + hi * 4 + i;
        int cc = w * 32 + n * 16 + lr;
        cout[((size_t)(t0 + tl) * B_ + b) * C_ + cc] = accC[m][n][i];
      }
}

// ---------------- reduce SP=2 comp partials into out ----------------
__global__ void k_comp_red(const float* __restrict__ P, float* __restrict__ comp) {
  size_t i = ((size_t)blockIdx.x * 256 + threadIdx.x) * 4;
  f32x4 a = *(const f32x4*)(P + i);
  f32x4 c = *(const f32x4*)(P + (size_t)T_ * B_ * C_ + i);
  f32x4 r;
#pragma unroll
  for (int e = 0; e < 4; ++e) r[e] = a[e] + c[e];
  *(f32x4*)(comp + i) = r;
}

// ---------------- launch ----------------
extern "C" void kernel_launch(void* const* d_in, const int* in_sizes, int n_in,
                              void* d_out, int out_size, void* d_ws, size_t ws_size,
                              hipStream_t stream) {
  const float* ctx = (const float*)d_in[0];
  const float* query = (const float*)d_in[1];
  const void* mask = d_in[2];
  const float* W = (const float*)d_in[3];

  float* out = (float*)d_out;
  float* attn = out;                               // [T][B][S] f32
  float* comp = out + (size_t)T_ * B_ * S_;        // [T][B][C] f32

  char* ws = (char*)d_ws;
  f16* ctxT = (f16*)(ws);                          // 16,777,216 B
  f16* qT = (f16*)(ws + 16777216);                 //  8,388,608 B
  f16* WT = (f16*)(ws + 25165824);                 //    131,072 B
  float* maskf = (float*)(ws + 25296896);          //    131,072 B
  float* rmax = (float*)(ws + 25427968);           //     65,536 B
  float* rsum = (float*)(ws + 25493504);           //     65,536 B
  int* allm = (int*)(ws + 25559040);
  int* mode = (int*)(ws + 25559072);
  float* pmax = (float*)(ws + 25559168);           //  4,194,304 B
  float* psum = (float*)(ws + 29753472);           //  4,194,304 B -> end 33,947,776

  // common preprocessing
  k_mask_mode<<<1, 256, 0, stream>>>((const unsigned char*)mask, mode, allm);
  k_expand_mask<<<(B_ * S_) / 256, 256, 0, stream>>>(mask, mode, maskf, allm);
  k_conv_w<<<(C_ * Q_) / 256, 256, 0, stream>>>(W, WT);
  k_conv_q<<<(T_ * B_ * Q_ / 4) / 256, 256, 0, stream>>>(query, qT);
  k_transpose_ctx<<<dim3(S_ / 64, C_ / 64, B_), 256, 0, stream>>>(ctx, ctxT);

  if (ws_size >= (size_t)84279424) {
    // BEST-MEASURED path (R12, 503.8us): CW in ws + SP=2 comp partials in ws
    f16* CW2 = (f16*)(ws + 33947776);              // 16,777,216 B -> end 50,724,992
    float* compP = (float*)(ws + 50724992);        // 33,554,432 B -> end 84,279,424
    k_gemm_cw<<<dim3(Q_ / 128, (B_ * S_) / 128), 256, 0, stream>>>(ctx, WT, CW2);
    k_stats5<<<dim3(8 * 32 * 16), 256, 0, stream>>>(qT, CW2, maskf, pmax, psum);
    k_finalize<<<NROW / 256, 256, 0, stream>>>(pmax, psum, rmax, rsum);
    k_fused4<<<dim3((T_ / 128) * B_ * 2), 512, 0, stream>>>(qT, CW2, ctxT, maskf, rmax, rsum,
                                                            allm, attn, compP);
    k_comp_red<<<(T_ * B_ * C_ / 4) / 256, 256, 0, stream>>>(compP, comp);
  } else {
    // FALLBACK: proven old path (CW aliases comp region; raw scores round-trip via attn)
    f16* CW = (f16*)comp;
    k_gemm_cw<<<dim3(Q_ / 128, (B_ * S_) / 128), 256, 0, stream>>>(ctx, WT, CW);
    k_gemm_scores<<<dim3(S_ / 128, T_ / 128, B_), 256, 0, stream>>>(qT, CW, maskf, attn, pmax, psum);
    k_finalize<<<NROW / 256, 256, 0, stream>>>(pmax, psum, rmax, rsum);
    k_comp<<<dim3(T_ / 32, B_), 256, 0, stream>>>(attn, ctxT, rmax, rsum, allm, comp);
  }
}